// Round 3
// baseline (117.798 us; speedup 1.0000x reference)
//
#include <hip/hip_runtime.h>

typedef unsigned short u16;
typedef unsigned int u32;
typedef __bf16 bf16x8 __attribute__((ext_vector_type(8)));
typedef float f32x4 __attribute__((ext_vector_type(4)));

// Prepped-weight layout in g_wbuf (bytes), rewritten fully by prep_kernel
// every launch (deterministic):
//   W1f @ 0      : 7kt*10nt*64lane*8elem u16 = 71680 B  (K 200->224, N 150->160, zero-padded)
//   W2f @ 71680  : 5kt*7nt*64lane*8elem u16  = 35840 B  (K 150->160, N 100->112, zero-padded)
//   b1p @ 107520 : 160 f32 (zero-padded)
//   b2p @ 108160 : 112 f32 (zero-padded)
#define W2F_OFF 71680
#define B1_OFF 107520
#define B2_OFF 108160
#define WS_BYTES 108608

__device__ __align__(256) unsigned char g_wbuf[WS_BYTES];

__device__ __forceinline__ u16 f2bf(float f) {
  u32 u = __builtin_bit_cast(u32, f);
  u = (u + 0x7FFFu + ((u >> 16) & 1u)) >> 16;  // RNE
  return (u16)u;
}

__global__ void prep_kernel(const float* __restrict__ W1, const float* __restrict__ b1,
                            const float* __restrict__ W2, const float* __restrict__ b2)
{
  const int stride = gridDim.x * blockDim.x;
  const int tid0 = blockIdx.x * blockDim.x + threadIdx.x;
  u16* w1f = (u16*)g_wbuf;
  for (int e = tid0; e < 35840; e += stride) {
    int j = e & 7, l = (e >> 3) & 63, nt = (e >> 9) % 10, kt = e / 5120;
    int k = kt * 32 + ((l >> 4) << 3) + j;
    int n = nt * 16 + (l & 15);
    w1f[e] = (k < 200 && n < 150) ? f2bf(W1[k * 150 + n]) : (u16)0;
  }
  u16* w2f = (u16*)(g_wbuf + W2F_OFF);
  for (int e = tid0; e < 17920; e += stride) {
    int j = e & 7, l = (e >> 3) & 63, nt = (e >> 9) % 7, kt = e / 3584;
    int k = kt * 32 + ((l >> 4) << 3) + j;
    int n = nt * 16 + (l & 15);
    w2f[e] = (k < 150 && n < 100) ? f2bf(W2[k * 100 + n]) : (u16)0;
  }
  float* b1p = (float*)(g_wbuf + B1_OFF);
  for (int e = tid0; e < 160; e += stride) b1p[e] = (e < 150) ? b1[e] : 0.f;
  float* b2p = (float*)(g_wbuf + B2_OFF);
  for (int e = tid0; e < 112; e += stride) b2p[e] = (e < 100) ? b2[e] : 0.f;
}

// 256 threads = 4 independent waves; each wave owns 32 rows (2 m-tiles).
// A-frags loaded directly from global x (coalesced 128B/row) + converted
// in flight. h1 handoff via wave-PRIVATE LDS region (5120 u16/wave) ->
// ZERO barriers. LDS 40960 B -> 4 blocks/CU; VGPR capped 128 -> 16 waves/CU.
__global__ __launch_bounds__(256, 4)
void fused_mlp(const float* __restrict__ x, float* __restrict__ out, int B)
{
  __shared__ __align__(16) u16 hs[20480];   // 4 waves * 5120

  const int tid = threadIdx.x;
  const int lane = tid & 63;
  const int wv = tid >> 6;
  const int cl = lane & 15, gr = lane >> 4;
  const long wr0 = ((long)blockIdx.x * 4 + wv) * 32;   // this wave's first row

  u16* hw = &hs[wv * 5120];                 // wave-private h1 fragment buffer
  const u16* w1g = (const u16*)g_wbuf;
  const u16* w2g = (const u16*)(g_wbuf + W2F_OFF);

  const float* xr0 = x + (wr0 + cl) * 200;  // row for mt0, this lane
  const float* xr1 = xr0 + 16 * 200;        // row for mt1
  const int kg = gr * 8;                    // lane-group k offset within kt

  const f32x4 zz = {0.f, 0.f, 0.f, 0.f};
  f32x4 acc1[2][10];
  #pragma unroll
  for (int i = 0; i < 2; ++i)
    #pragma unroll
    for (int nt = 0; nt < 10; ++nt) acc1[i][nt] = zz;

  // ---- GEMM1: [32 x 224] @ [224 x 160], A direct-from-global ----
  #pragma unroll
  for (int kt = 0; kt < 7; ++kt) {
    const int k0 = kt * 32 + kg;
    bf16x8 a0, a1;
    union { bf16x8 v; u32 w[4]; } A0, A1;
    if (k0 < 200) {                         // only kt==6, gr>=1 is padded
      float4 u0 = *reinterpret_cast<const float4*>(xr0 + k0);
      float4 v0 = *reinterpret_cast<const float4*>(xr0 + k0 + 4);
      float4 u1 = *reinterpret_cast<const float4*>(xr1 + k0);
      float4 v1 = *reinterpret_cast<const float4*>(xr1 + k0 + 4);
      A0.w[0] = (u32)f2bf(u0.x) | ((u32)f2bf(u0.y) << 16);
      A0.w[1] = (u32)f2bf(u0.z) | ((u32)f2bf(u0.w) << 16);
      A0.w[2] = (u32)f2bf(v0.x) | ((u32)f2bf(v0.y) << 16);
      A0.w[3] = (u32)f2bf(v0.z) | ((u32)f2bf(v0.w) << 16);
      A1.w[0] = (u32)f2bf(u1.x) | ((u32)f2bf(u1.y) << 16);
      A1.w[1] = (u32)f2bf(u1.z) | ((u32)f2bf(u1.w) << 16);
      A1.w[2] = (u32)f2bf(v1.x) | ((u32)f2bf(v1.y) << 16);
      A1.w[3] = (u32)f2bf(v1.z) | ((u32)f2bf(v1.w) << 16);
    } else {
      A0.w[0] = A0.w[1] = A0.w[2] = A0.w[3] = 0u;
      A1.w[0] = A1.w[1] = A1.w[2] = A1.w[3] = 0u;
    }
    a0 = A0.v; a1 = A1.v;
    #pragma unroll
    for (int nt = 0; nt < 10; ++nt) {
      bf16x8 b = *reinterpret_cast<const bf16x8*>(w1g + ((kt * 10 + nt) * 64 + lane) * 8);
      acc1[0][nt] = __builtin_amdgcn_mfma_f32_16x16x32_bf16(a0, b, acc1[0][nt], 0, 0, 0);
      acc1[1][nt] = __builtin_amdgcn_mfma_f32_16x16x32_bf16(a1, b, acc1[1][nt], 0, 0, 0);
    }
  }

  // ---- epilogue 1: bias + leaky, out1 row-means, h1 -> wave-private LDS ----
  const float* b1p = (const float*)(g_wbuf + B1_OFF);
  float b1v[10];
  #pragma unroll
  for (int nt = 0; nt < 10; ++nt) b1v[nt] = b1p[nt * 16 + cl];

  float rs0[4] = {0, 0, 0, 0}, rs1[4] = {0, 0, 0, 0};
  #pragma unroll
  for (int nt = 0; nt < 10; ++nt) {
    int k2 = nt * 16 + cl;                  // h1 column = GEMM2 k index
    int kt2 = k2 >> 5;
    int l2base = 16 * ((k2 & 31) >> 3);
    int e2 = k2 & 7;
    #pragma unroll
    for (int j = 0; j < 4; ++j) {
      int l2 = gr * 4 + j + l2base;         // C/D: row=(lane>>4)*4+reg, col=lane&15
      float h = acc1[0][nt][j] + b1v[nt];
      h = (h >= 0.f) ? h : 0.1f * h;
      rs0[j] += h;
      hw[(kt2 * 64 + l2) * 8 + e2] = f2bf(h);
      float g = acc1[1][nt][j] + b1v[nt];
      g = (g >= 0.f) ? g : 0.1f * g;
      rs1[j] += g;
      hw[((5 + kt2) * 64 + l2) * 8 + e2] = f2bf(g);
    }
  }
  #pragma unroll
  for (int j = 0; j < 4; ++j) {
    float s0 = rs0[j], s1 = rs1[j];
    #pragma unroll
    for (int mask = 1; mask < 16; mask <<= 1) {
      s0 += __shfl_xor(s0, mask, 64);
      s1 += __shfl_xor(s1, mask, 64);
    }
    if (cl == 0) {
      out[wr0 + gr * 4 + j]      = s0 * (1.f / 150.f);
      out[wr0 + 16 + gr * 4 + j] = s1 * (1.f / 150.f);
    }
  }

  // ---- GEMM2: [32 x 160] @ [160 x 112], A from wave-private LDS ----
  f32x4 acc2[2][7];
  #pragma unroll
  for (int i = 0; i < 2; ++i)
    #pragma unroll
    for (int nt = 0; nt < 7; ++nt) acc2[i][nt] = zz;

  #pragma unroll
  for (int kt = 0; kt < 5; ++kt) {
    bf16x8 a0 = *reinterpret_cast<const bf16x8*>(&hw[(kt * 64 + lane) * 8]);
    bf16x8 a1 = *reinterpret_cast<const bf16x8*>(&hw[((5 + kt) * 64 + lane) * 8]);
    #pragma unroll
    for (int nt = 0; nt < 7; ++nt) {
      bf16x8 b = *reinterpret_cast<const bf16x8*>(w2g + ((kt * 7 + nt) * 64 + lane) * 8);
      acc2[0][nt] = __builtin_amdgcn_mfma_f32_16x16x32_bf16(a0, b, acc2[0][nt], 0, 0, 0);
      acc2[1][nt] = __builtin_amdgcn_mfma_f32_16x16x32_bf16(a1, b, acc2[1][nt], 0, 0, 0);
    }
  }

  // ---- epilogue 2: bias + leaky, out2 row-means ----
  const float* b2p = (const float*)(g_wbuf + B2_OFF);
  float b2v[7];
  #pragma unroll
  for (int nt = 0; nt < 7; ++nt) b2v[nt] = b2p[nt * 16 + cl];

  float t0[4] = {0, 0, 0, 0}, t1[4] = {0, 0, 0, 0};
  #pragma unroll
  for (int nt = 0; nt < 7; ++nt) {
    #pragma unroll
    for (int j = 0; j < 4; ++j) {
      float h = acc2[0][nt][j] + b2v[nt];
      h = (h >= 0.f) ? h : 0.1f * h;
      t0[j] += h;
      float g = acc2[1][nt][j] + b2v[nt];
      g = (g >= 0.f) ? g : 0.1f * g;
      t1[j] += g;
    }
  }
  #pragma unroll
  for (int j = 0; j < 4; ++j) {
    float s0 = t0[j], s1 = t1[j];
    #pragma unroll
    for (int mask = 1; mask < 16; mask <<= 1) {
      s0 += __shfl_xor(s0, mask, 64);
      s1 += __shfl_xor(s1, mask, 64);
    }
    if (cl == 0) {
      out[B + wr0 + gr * 4 + j]      = s0 * (1.f / 100.f);
      out[B + wr0 + 16 + gr * 4 + j] = s1 * (1.f / 100.f);
    }
  }
}

extern "C" void kernel_launch(void* const* d_in, const int* in_sizes, int n_in,
                              void* d_out, int out_size, void* d_ws, size_t ws_size,
                              hipStream_t stream)
{
  const float* x  = (const float*)d_in[0];
  const float* W1 = (const float*)d_in[1];
  const float* b1 = (const float*)d_in[2];
  const float* W2 = (const float*)d_in[3];
  const float* b2 = (const float*)d_in[4];
  float* out = (float*)d_out;
  const int B = in_sizes[0] / 200;   // 262144

  prep_kernel<<<64, 256, 0, stream>>>(W1, b1, W2, b2);
  fused_mlp<<<B / 128, 256, 0, stream>>>(x, out, B);
}

// Round 4
// 93.957 us; speedup vs baseline: 1.2538x; 1.2538x over previous
//
#include <hip/hip_runtime.h>

typedef unsigned short u16;
typedef unsigned int u32;
typedef __bf16 bf16x8 __attribute__((ext_vector_type(8)));
typedef float f32x4 __attribute__((ext_vector_type(4)));

// Prepped-weight layout in g_wbuf (bytes), rewritten fully by prep_kernel
// every launch (deterministic):
//   W1f @ 0      : 7kt*10nt*64lane*8elem u16 = 71680 B  (K 200->224, N 150->160, zero-padded)
//   W2f @ 71680  : 5kt*7nt*64lane*8elem u16  = 35840 B  (K 150->160, N 100->112, zero-padded)
//   b1p @ 107520 : 160 f32 (zero-padded)
//   b2p @ 108160 : 112 f32 (zero-padded)
#define W2F_OFF 71680
#define B1_OFF 107520
#define B2_OFF 108160
#define WS_BYTES 108608

__device__ __align__(256) unsigned char g_wbuf[WS_BYTES];

__device__ __forceinline__ u16 f2bf(float f) {
  u32 u = __builtin_bit_cast(u32, f);
  u = (u + 0x7FFFu + ((u >> 16) & 1u)) >> 16;  // RNE
  return (u16)u;
}

__global__ void prep_kernel(const float* __restrict__ W1, const float* __restrict__ b1,
                            const float* __restrict__ W2, const float* __restrict__ b2)
{
  const int stride = gridDim.x * blockDim.x;
  const int tid0 = blockIdx.x * blockDim.x + threadIdx.x;
  u16* w1f = (u16*)g_wbuf;
  for (int e = tid0; e < 35840; e += stride) {
    int j = e & 7, l = (e >> 3) & 63, nt = (e >> 9) % 10, kt = e / 5120;
    int k = kt * 32 + ((l >> 4) << 3) + j;
    int n = nt * 16 + (l & 15);
    w1f[e] = (k < 200 && n < 150) ? f2bf(W1[k * 150 + n]) : (u16)0;
  }
  u16* w2f = (u16*)(g_wbuf + W2F_OFF);
  for (int e = tid0; e < 17920; e += stride) {
    int j = e & 7, l = (e >> 3) & 63, nt = (e >> 9) % 7, kt = e / 3584;
    int k = kt * 32 + ((l >> 4) << 3) + j;
    int n = nt * 16 + (l & 15);
    w2f[e] = (k < 150 && n < 100) ? f2bf(W2[k * 100 + n]) : (u16)0;
  }
  float* b1p = (float*)(g_wbuf + B1_OFF);
  for (int e = tid0; e < 160; e += stride) b1p[e] = (e < 150) ? b1[e] : 0.f;
  float* b2p = (float*)(g_wbuf + B2_OFF);
  for (int e = tid0; e < 112; e += stride) b2p[e] = (e < 100) ? b2[e] : 0.f;
}

// BM=64 rows/block, 128 threads (2 waves), wave w owns m-tiles {2w, 2w+1}.
// x staged coalesced into frag-major LDS for kt 0..5 (24576 B) + compact
// 1KB region for k=192..199 (kt=6 real lanes); kt=6 pad lanes zeroed in
// regs. LDS 25600 B -> 6 blocks/CU; launch_bounds(128,3) -> <=170 regs
// -> 12 waves/CU (37.5%). Same 3-barrier replay-stable structure as R2.
__global__ __launch_bounds__(128, 3)
void fused_mlp(const float* __restrict__ x, float* __restrict__ out, int B)
{
  __shared__ __align__(16) u16 xs[12800];   // 24576B frags + 1024B compact

  const int tid = threadIdx.x;
  const int lane = tid & 63;
  const int wv = tid >> 6;                  // 0..1
  const int cl = lane & 15, gr = lane >> 4;
  const long r0 = (long)blockIdx.x * 64;

  // ---- stage x tile: coalesced float4 -> bf16 frag-major LDS ----
  const float* xg = x + r0 * 200;
  #pragma unroll
  for (int i = 0; i < 25; ++i) {
    int c = tid + i * 128;                  // 64 rows * 50 float4-chunks
    int row = c / 50, kc = c % 50;
    float4 v = *reinterpret_cast<const float4*>(xg + row * 200 + kc * 4);
    int k0 = kc * 4;
    int mt = row >> 4;
    int idx;
    if (k0 < 192) {
      int fl = (row & 15) | (((k0 & 31) >> 3) << 4);
      idx = ((mt * 6 + (k0 >> 5)) * 64 + fl) * 8 + (k0 & 7);
    } else {                                // k 192..199 -> compact region
      idx = 12288 + mt * 128 + (row & 15) * 8 + (k0 - 192);
    }
    uint2 p;
    p.x = (u32)f2bf(v.x) | ((u32)f2bf(v.y) << 16);
    p.y = (u32)f2bf(v.z) | ((u32)f2bf(v.w) << 16);
    *reinterpret_cast<uint2*>(&xs[idx]) = p;
  }
  __syncthreads();   // (1) xs fully staged

  const int mt0 = wv * 2, mt1 = wv * 2 + 1;
  const u16* w1g = (const u16*)g_wbuf;
  const u16* w2g = (const u16*)(g_wbuf + W2F_OFF);

  const f32x4 zz = {0.f, 0.f, 0.f, 0.f};
  f32x4 acc1[2][10];
  #pragma unroll
  for (int i = 0; i < 2; ++i)
    #pragma unroll
    for (int nt = 0; nt < 10; ++nt) acc1[i][nt] = zz;

  // ---- GEMM1: [32 x 224] @ [224 x 160] per wave ----
  #pragma unroll
  for (int kt = 0; kt < 7; ++kt) {
    bf16x8 bfr[10];
    #pragma unroll
    for (int nt = 0; nt < 10; ++nt)
      bfr[nt] = *reinterpret_cast<const bf16x8*>(w1g + ((kt * 10 + nt) * 64 + lane) * 8);
    bf16x8 a0, a1;
    if (kt < 6) {
      a0 = *reinterpret_cast<const bf16x8*>(&xs[((mt0 * 6 + kt) * 64 + lane) * 8]);
      a1 = *reinterpret_cast<const bf16x8*>(&xs[((mt1 * 6 + kt) * 64 + lane) * 8]);
    } else {                                // kt==6: k 192..223, only gr==0 real
      union { bf16x8 v; u32 w[4]; } A0, A1;
      A0.v = *reinterpret_cast<const bf16x8*>(&xs[12288 + mt0 * 128 + cl * 8]);
      A1.v = *reinterpret_cast<const bf16x8*>(&xs[12288 + mt1 * 128 + cl * 8]);
      if (gr != 0) {
        A0.w[0] = A0.w[1] = A0.w[2] = A0.w[3] = 0u;
        A1.w[0] = A1.w[1] = A1.w[2] = A1.w[3] = 0u;
      }
      a0 = A0.v; a1 = A1.v;
    }
    #pragma unroll
    for (int nt = 0; nt < 10; ++nt) {
      acc1[0][nt] = __builtin_amdgcn_mfma_f32_16x16x32_bf16(a0, bfr[nt], acc1[0][nt], 0, 0, 0);
      acc1[1][nt] = __builtin_amdgcn_mfma_f32_16x16x32_bf16(a1, bfr[nt], acc1[1][nt], 0, 0, 0);
    }
  }
  __syncthreads();   // (2) all GEMM1 A-reads done before h1 overwrites xs

  // ---- epilogue 1: bias + leaky, out1 row-means, h1 -> xs as GEMM2 A-frags ----
  const float* b1p = (const float*)(g_wbuf + B1_OFF);
  float b1v[10];
  #pragma unroll
  for (int nt = 0; nt < 10; ++nt) b1v[nt] = b1p[nt * 16 + cl];

  float rs0[4] = {0, 0, 0, 0}, rs1[4] = {0, 0, 0, 0};
  #pragma unroll
  for (int nt = 0; nt < 10; ++nt) {
    int k2 = nt * 16 + cl;                  // h1 column = GEMM2 k index
    int kt2 = k2 >> 5;
    int l2base = 16 * ((k2 & 31) >> 3);
    int e2 = k2 & 7;
    #pragma unroll
    for (int j = 0; j < 4; ++j) {
      int l2 = gr * 4 + j + l2base;         // C/D: row=(lane>>4)*4+reg, col=lane&15
      float h = acc1[0][nt][j] + b1v[nt];
      h = (h >= 0.f) ? h : 0.1f * h;
      rs0[j] += h;
      xs[((mt0 * 5 + kt2) * 64 + l2) * 8 + e2] = f2bf(h);
      float g = acc1[1][nt][j] + b1v[nt];
      g = (g >= 0.f) ? g : 0.1f * g;
      rs1[j] += g;
      xs[((mt1 * 5 + kt2) * 64 + l2) * 8 + e2] = f2bf(g);
    }
  }
  #pragma unroll
  for (int j = 0; j < 4; ++j) {
    float s0 = rs0[j], s1 = rs1[j];
    #pragma unroll
    for (int mask = 1; mask < 16; mask <<= 1) {
      s0 += __shfl_xor(s0, mask, 64);
      s1 += __shfl_xor(s1, mask, 64);
    }
    if (cl == 0) {
      out[r0 + mt0 * 16 + gr * 4 + j] = s0 * (1.f / 150.f);
      out[r0 + mt1 * 16 + gr * 4 + j] = s1 * (1.f / 150.f);
    }
  }
  __syncthreads();   // (3) h1 frags fully written before GEMM2 reads

  // ---- GEMM2: [32 x 160] @ [160 x 112] per wave ----
  f32x4 acc2[2][7];
  #pragma unroll
  for (int i = 0; i < 2; ++i)
    #pragma unroll
    for (int nt = 0; nt < 7; ++nt) acc2[i][nt] = zz;

  #pragma unroll
  for (int kt = 0; kt < 5; ++kt) {
    bf16x8 bfr[7];
    #pragma unroll
    for (int nt = 0; nt < 7; ++nt)
      bfr[nt] = *reinterpret_cast<const bf16x8*>(w2g + ((kt * 7 + nt) * 64 + lane) * 8);
    bf16x8 a0 = *reinterpret_cast<const bf16x8*>(&xs[((mt0 * 5 + kt) * 64 + lane) * 8]);
    bf16x8 a1 = *reinterpret_cast<const bf16x8*>(&xs[((mt1 * 5 + kt) * 64 + lane) * 8]);
    #pragma unroll
    for (int nt = 0; nt < 7; ++nt) {
      acc2[0][nt] = __builtin_amdgcn_mfma_f32_16x16x32_bf16(a0, bfr[nt], acc2[0][nt], 0, 0, 0);
      acc2[1][nt] = __builtin_amdgcn_mfma_f32_16x16x32_bf16(a1, bfr[nt], acc2[1][nt], 0, 0, 0);
    }
  }

  // ---- epilogue 2: bias + leaky, out2 row-means ----
  const float* b2p = (const float*)(g_wbuf + B2_OFF);
  float b2v[7];
  #pragma unroll
  for (int nt = 0; nt < 7; ++nt) b2v[nt] = b2p[nt * 16 + cl];

  float t0[4] = {0, 0, 0, 0}, t1[4] = {0, 0, 0, 0};
  #pragma unroll
  for (int nt = 0; nt < 7; ++nt) {
    #pragma unroll
    for (int j = 0; j < 4; ++j) {
      float h = acc2[0][nt][j] + b2v[nt];
      h = (h >= 0.f) ? h : 0.1f * h;
      t0[j] += h;
      float g = acc2[1][nt][j] + b2v[nt];
      g = (g >= 0.f) ? g : 0.1f * g;
      t1[j] += g;
    }
  }
  #pragma unroll
  for (int j = 0; j < 4; ++j) {
    float s0 = t0[j], s1 = t1[j];
    #pragma unroll
    for (int mask = 1; mask < 16; mask <<= 1) {
      s0 += __shfl_xor(s0, mask, 64);
      s1 += __shfl_xor(s1, mask, 64);
    }
    if (cl == 0) {
      out[B + r0 + mt0 * 16 + gr * 4 + j] = s0 * (1.f / 100.f);
      out[B + r0 + mt1 * 16 + gr * 4 + j] = s1 * (1.f / 100.f);
    }
  }
}

extern "C" void kernel_launch(void* const* d_in, const int* in_sizes, int n_in,
                              void* d_out, int out_size, void* d_ws, size_t ws_size,
                              hipStream_t stream)
{
  const float* x  = (const float*)d_in[0];
  const float* W1 = (const float*)d_in[1];
  const float* b1 = (const float*)d_in[2];
  const float* W2 = (const float*)d_in[3];
  const float* b2 = (const float*)d_in[4];
  float* out = (float*)d_out;
  const int B = in_sizes[0] / 200;   // 262144

  prep_kernel<<<64, 256, 0, stream>>>(W1, b1, W2, b2);
  fused_mlp<<<B / 64, 128, 0, stream>>>(x, out, B);
}

// Round 5
// 73.351 us; speedup vs baseline: 1.6060x; 1.2809x over previous
//
#include <hip/hip_runtime.h>

typedef unsigned short u16;
typedef unsigned int u32;
typedef __bf16 bf16x8 __attribute__((ext_vector_type(8)));
typedef float f32x4 __attribute__((ext_vector_type(4)));

// Prepped-weight layout in g_wbuf (bytes), rewritten fully by prep_kernel
// every launch (deterministic):
//   W1f @ 0      : 7kt*10nt*64lane*8elem u16 = 71680 B  (K 200->224, N 150->160, zero-padded)
//   W2f @ 71680  : 5kt*7nt*64lane*8elem u16  = 35840 B  (K 150->160, N 100->112, zero-padded)
//   b1p @ 107520 : 160 f32 (zero-padded)
//   b2p @ 108160 : 112 f32 (zero-padded)
#define W2F_OFF 71680
#define B1_OFF 107520
#define B2_OFF 108160
#define WS_BYTES 108608

__device__ __align__(256) unsigned char g_wbuf[WS_BYTES];

__device__ __forceinline__ u16 f2bf(float f) {
  u32 u = __builtin_bit_cast(u32, f);
  u = (u + 0x7FFFu + ((u >> 16) & 1u)) >> 16;  // RNE
  return (u16)u;
}

__global__ void prep_kernel(const float* __restrict__ W1, const float* __restrict__ b1,
                            const float* __restrict__ W2, const float* __restrict__ b2)
{
  const int stride = gridDim.x * blockDim.x;
  const int tid0 = blockIdx.x * blockDim.x + threadIdx.x;
  u16* w1f = (u16*)g_wbuf;
  for (int e = tid0; e < 35840; e += stride) {
    int j = e & 7, l = (e >> 3) & 63, nt = (e >> 9) % 10, kt = e / 5120;
    int k = kt * 32 + ((l >> 4) << 3) + j;
    int n = nt * 16 + (l & 15);
    w1f[e] = (k < 200 && n < 150) ? f2bf(W1[k * 150 + n]) : (u16)0;
  }
  u16* w2f = (u16*)(g_wbuf + W2F_OFF);
  for (int e = tid0; e < 17920; e += stride) {
    int j = e & 7, l = (e >> 3) & 63, nt = (e >> 9) % 7, kt = e / 3584;
    int k = kt * 32 + ((l >> 4) << 3) + j;
    int n = nt * 16 + (l & 15);
    w2f[e] = (k < 150 && n < 100) ? f2bf(W2[k * 100 + n]) : (u16)0;
  }
  float* b1p = (float*)(g_wbuf + B1_OFF);
  for (int e = tid0; e < 160; e += stride) b1p[e] = (e < 150) ? b1[e] : 0.f;
  float* b2p = (float*)(g_wbuf + B2_OFF);
  for (int e = tid0; e < 112; e += stride) b2p[e] = (e < 100) ? b2[e] : 0.f;
}

// BM=64, 256 threads (4 waves). Wave-pair pr = wv>>1 owns rows 32pr..32pr+31
// (m-tiles 2pr, 2pr+1); within a pair, wave half h = wv&1 computes the n-tile
// half (GEMM1: nt 5h..5h+4; GEMM2: nt 4h..4h+3 resp 3). acc1 80->40 regs,
// acc2 56->32 -> fits launch_bounds(256,4) cap 128 with NO spill, and leaves
// room for a one-kt-lookahead B-frag pipeline. 4 phase barriers, no
// double-buffer races. LDS 26624 B -> 16 waves/CU (50%) reg-capped.
__global__ __launch_bounds__(256, 4)
void fused_mlp(const float* __restrict__ x, float* __restrict__ out, int B)
{
  __shared__ __align__(16) u16 xs[12800];   // 24576B frags + 512B compact + pad
  __shared__ float ps[2][2][64];            // [phase][half][block row] partial sums

  const int tid = threadIdx.x;
  const int lane = tid & 63;
  const int wv = tid >> 6;                  // 0..3
  const int h = wv & 1;                     // n-half
  const int pr = wv >> 1;                   // row pair
  const int cl = lane & 15, gr = lane >> 4;
  const long r0 = (long)blockIdx.x * 64;

  const u16* w1g = (const u16*)g_wbuf;
  const u16* w2g = (const u16*)(g_wbuf + W2F_OFF);

  // ---- stage x tile: coalesced float4 -> bf16 frag-major LDS ----
  const float* xg = x + r0 * 200;
  #pragma unroll
  for (int i = 0; i < 13; ++i) {
    int c = tid + i * 256;                  // 64 rows * 50 float4-chunks = 3200
    if (c < 3200) {
      int row = c / 50, kc = c % 50;
      float4 v = *reinterpret_cast<const float4*>(xg + row * 200 + kc * 4);
      int k0 = kc * 4;
      int mt = row >> 4;
      int idx;
      if (k0 < 192) {
        int fl = (row & 15) | (((k0 & 31) >> 3) << 4);
        idx = ((mt * 6 + (k0 >> 5)) * 64 + fl) * 8 + (k0 & 7);
      } else {                              // k 192..199 -> compact region
        idx = 12288 + mt * 128 + (row & 15) * 8 + (k0 - 192);
      }
      uint2 p;
      p.x = (u32)f2bf(v.x) | ((u32)f2bf(v.y) << 16);
      p.y = (u32)f2bf(v.z) | ((u32)f2bf(v.w) << 16);
      *reinterpret_cast<uint2*>(&xs[idx]) = p;
    }
  }

  // preload kt=0 B-frags (no xs dependency -> before the barrier)
  bf16x8 bfr[5];
  #pragma unroll
  for (int nt = 0; nt < 5; ++nt)
    bfr[nt] = *reinterpret_cast<const bf16x8*>(w1g + ((0 * 10 + 5 * h + nt) * 64 + lane) * 8);

  __syncthreads();   // (1) xs fully staged

  const int mt0 = pr * 2, mt1 = pr * 2 + 1;
  const f32x4 zz = {0.f, 0.f, 0.f, 0.f};
  f32x4 acc1[2][5];
  #pragma unroll
  for (int i = 0; i < 2; ++i)
    #pragma unroll
    for (int nt = 0; nt < 5; ++nt) acc1[i][nt] = zz;

  // ---- GEMM1: [32 x 224] @ [224 x 80] per wave, 1-kt-lookahead pipeline ----
  #pragma unroll
  for (int kt = 0; kt < 7; ++kt) {
    bf16x8 bnx[5];
    if (kt < 6) {
      #pragma unroll
      for (int nt = 0; nt < 5; ++nt)
        bnx[nt] = *reinterpret_cast<const bf16x8*>(w1g + (((kt + 1) * 10 + 5 * h + nt) * 64 + lane) * 8);
    }
    bf16x8 a0, a1;
    if (kt < 6) {
      a0 = *reinterpret_cast<const bf16x8*>(&xs[((mt0 * 6 + kt) * 64 + lane) * 8]);
      a1 = *reinterpret_cast<const bf16x8*>(&xs[((mt1 * 6 + kt) * 64 + lane) * 8]);
    } else {                                // kt==6: k 192..223, only gr==0 real
      union { bf16x8 v; u32 w[4]; } A0, A1;
      A0.v = *reinterpret_cast<const bf16x8*>(&xs[12288 + mt0 * 128 + cl * 8]);
      A1.v = *reinterpret_cast<const bf16x8*>(&xs[12288 + mt1 * 128 + cl * 8]);
      if (gr != 0) {
        A0.w[0] = A0.w[1] = A0.w[2] = A0.w[3] = 0u;
        A1.w[0] = A1.w[1] = A1.w[2] = A1.w[3] = 0u;
      }
      a0 = A0.v; a1 = A1.v;
    }
    #pragma unroll
    for (int nt = 0; nt < 5; ++nt) {
      acc1[0][nt] = __builtin_amdgcn_mfma_f32_16x16x32_bf16(a0, bfr[nt], acc1[0][nt], 0, 0, 0);
      acc1[1][nt] = __builtin_amdgcn_mfma_f32_16x16x32_bf16(a1, bfr[nt], acc1[1][nt], 0, 0, 0);
    }
    if (kt < 6) {
      #pragma unroll
      for (int nt = 0; nt < 5; ++nt) bfr[nt] = bnx[nt];
    }
  }
  __syncthreads();   // (2) all GEMM1 A-reads done before h1 overwrites xs

  // ---- epilogue 1: bias + leaky, out1 partials, h1 -> xs as GEMM2 A-frags ----
  const float* b1p = (const float*)(g_wbuf + B1_OFF);
  float b1v[5];
  #pragma unroll
  for (int nt = 0; nt < 5; ++nt) b1v[nt] = b1p[(5 * h + nt) * 16 + cl];

  float rs0[4] = {0, 0, 0, 0}, rs1[4] = {0, 0, 0, 0};
  #pragma unroll
  for (int nt = 0; nt < 5; ++nt) {
    int k2 = (5 * h + nt) * 16 + cl;        // h1 column = GEMM2 k index
    int kt2 = k2 >> 5;
    int l2base = 16 * ((k2 & 31) >> 3);
    int e2 = k2 & 7;
    #pragma unroll
    for (int j = 0; j < 4; ++j) {
      int l2 = gr * 4 + j + l2base;         // C/D: row=(lane>>4)*4+reg, col=lane&15
      float hv = acc1[0][nt][j] + b1v[nt];
      hv = (hv >= 0.f) ? hv : 0.1f * hv;
      rs0[j] += hv;
      xs[((mt0 * 5 + kt2) * 64 + l2) * 8 + e2] = f2bf(hv);
      float gv = acc1[1][nt][j] + b1v[nt];
      gv = (gv >= 0.f) ? gv : 0.1f * gv;
      rs1[j] += gv;
      xs[((mt1 * 5 + kt2) * 64 + l2) * 8 + e2] = f2bf(gv);
    }
  }
  #pragma unroll
  for (int j = 0; j < 4; ++j) {
    float s0 = rs0[j], s1 = rs1[j];
    #pragma unroll
    for (int mask = 1; mask < 16; mask <<= 1) {
      s0 += __shfl_xor(s0, mask, 64);
      s1 += __shfl_xor(s1, mask, 64);
    }
    if (cl == 0) {
      ps[0][h][mt0 * 16 + gr * 4 + j] = s0;
      ps[0][h][mt1 * 16 + gr * 4 + j] = s1;
    }
  }
  __syncthreads();   // (3) h1 frags + out1 partials visible

  if (wv == 0)       // finalize out1 (64 rows, one lane each)
    out[r0 + lane] = (ps[0][0][lane] + ps[0][1][lane]) * (1.f / 150.f);

  // ---- GEMM2: [32 x 160] @ [160 x 64/48] per wave, pipelined ----
  f32x4 acc2[2][4];
  #pragma unroll
  for (int i = 0; i < 2; ++i)
    #pragma unroll
    for (int nt = 0; nt < 4; ++nt) acc2[i][nt] = zz;

  bf16x8 b2r[4];
  #pragma unroll
  for (int nt = 0; nt < 4; ++nt)
    if (nt < 3 || h == 0)
      b2r[nt] = *reinterpret_cast<const bf16x8*>(w2g + ((0 * 7 + 4 * h + nt) * 64 + lane) * 8);

  #pragma unroll
  for (int kt = 0; kt < 5; ++kt) {
    bf16x8 bnx[4];
    if (kt < 4) {
      #pragma unroll
      for (int nt = 0; nt < 4; ++nt)
        if (nt < 3 || h == 0)
          bnx[nt] = *reinterpret_cast<const bf16x8*>(w2g + (((kt + 1) * 7 + 4 * h + nt) * 64 + lane) * 8);
    }
    bf16x8 a0 = *reinterpret_cast<const bf16x8*>(&xs[((mt0 * 5 + kt) * 64 + lane) * 8]);
    bf16x8 a1 = *reinterpret_cast<const bf16x8*>(&xs[((mt1 * 5 + kt) * 64 + lane) * 8]);
    #pragma unroll
    for (int nt = 0; nt < 4; ++nt) {
      if (nt < 3 || h == 0) {
        acc2[0][nt] = __builtin_amdgcn_mfma_f32_16x16x32_bf16(a0, b2r[nt], acc2[0][nt], 0, 0, 0);
        acc2[1][nt] = __builtin_amdgcn_mfma_f32_16x16x32_bf16(a1, b2r[nt], acc2[1][nt], 0, 0, 0);
      }
    }
    if (kt < 4) {
      #pragma unroll
      for (int nt = 0; nt < 4; ++nt)
        if (nt < 3 || h == 0) b2r[nt] = bnx[nt];
    }
  }

  // ---- epilogue 2: bias + leaky, out2 partials ----
  const float* b2p = (const float*)(g_wbuf + B2_OFF);
  float b2v[4];
  #pragma unroll
  for (int nt = 0; nt < 4; ++nt)
    b2v[nt] = (nt < 3 || h == 0) ? b2p[(4 * h + nt) * 16 + cl] : 0.f;

  float t0[4] = {0, 0, 0, 0}, t1[4] = {0, 0, 0, 0};
  #pragma unroll
  for (int nt = 0; nt < 4; ++nt) {
    if (nt < 3 || h == 0) {
      #pragma unroll
      for (int j = 0; j < 4; ++j) {
        float hv = acc2[0][nt][j] + b2v[nt];
        hv = (hv >= 0.f) ? hv : 0.1f * hv;
        t0[j] += hv;
        float gv = acc2[1][nt][j] + b2v[nt];
        gv = (gv >= 0.f) ? gv : 0.1f * gv;
        t1[j] += gv;
      }
    }
  }
  #pragma unroll
  for (int j = 0; j < 4; ++j) {
    float s0 = t0[j], s1 = t1[j];
    #pragma unroll
    for (int mask = 1; mask < 16; mask <<= 1) {
      s0 += __shfl_xor(s0, mask, 64);
      s1 += __shfl_xor(s1, mask, 64);
    }
    if (cl == 0) {
      ps[1][h][mt0 * 16 + gr * 4 + j] = s0;
      ps[1][h][mt1 * 16 + gr * 4 + j] = s1;
    }
  }
  __syncthreads();   // (4) out2 partials visible

  if (wv == 0)
    out[B + r0 + lane] = (ps[1][0][lane] + ps[1][1][lane]) * (1.f / 100.f);
}

extern "C" void kernel_launch(void* const* d_in, const int* in_sizes, int n_in,
                              void* d_out, int out_size, void* d_ws, size_t ws_size,
                              hipStream_t stream)
{
  const float* x  = (const float*)d_in[0];
  const float* W1 = (const float*)d_in[1];
  const float* b1 = (const float*)d_in[2];
  const float* W2 = (const float*)d_in[3];
  const float* b2 = (const float*)d_in[4];
  float* out = (float*)d_out;
  const int B = in_sizes[0] / 200;   // 262144

  prep_kernel<<<64, 256, 0, stream>>>(W1, b1, W2, b2);
  fused_mlp<<<B / 64, 256, 0, stream>>>(x, out, B);
}

// Round 7
// 71.492 us; speedup vs baseline: 1.6477x; 1.0260x over previous
//
#include <hip/hip_runtime.h>

typedef unsigned short u16;
typedef unsigned int u32;
typedef __bf16 bf16x8 __attribute__((ext_vector_type(8)));
typedef float f32x4 __attribute__((ext_vector_type(4)));

// Prepped-weight layout in g_wbuf (bytes), rewritten fully by prep_kernel
// every launch (deterministic):
//   W1f @ 0      : 7kt*10nt*64lane*8elem u16 = 71680 B  (K 200->224, N 150->160, zero-padded)
//   W2f @ 71680  : 5kt*7nt*64lane*8elem u16  = 35840 B  (K 150->160, N 100->112, zero-padded)
//   b1p @ 107520 : 160 f32 (zero-padded)
//   b2p @ 108160 : 112 f32 (zero-padded)
#define W2F_OFF 71680
#define B1_OFF 107520
#define B2_OFF 108160
#define WS_BYTES 108608

__device__ __align__(256) unsigned char g_wbuf[WS_BYTES];

__device__ __forceinline__ u16 f2bf(float f) {
  __bf16 b = (__bf16)f;                    // hw RNE convert; scalar-cast path
  return __builtin_bit_cast(u16, b);
}
__device__ __forceinline__ u32 pk2bf(float a, float b) {
  return (u32)f2bf(a) | ((u32)f2bf(b) << 16);  // compiler fuses to v_cvt_pk_bf16_f32
}

__global__ void prep_kernel(const float* __restrict__ W1, const float* __restrict__ b1,
                            const float* __restrict__ W2, const float* __restrict__ b2)
{
  const int stride = gridDim.x * blockDim.x;
  const int tid0 = blockIdx.x * blockDim.x + threadIdx.x;
  u16* w1f = (u16*)g_wbuf;
  for (int e = tid0; e < 35840; e += stride) {
    int j = e & 7, l = (e >> 3) & 63, nt = (e >> 9) % 10, kt = e / 5120;
    int k = kt * 32 + ((l >> 4) << 3) + j;
    int n = nt * 16 + (l & 15);
    w1f[e] = (k < 200 && n < 150) ? f2bf(W1[k * 150 + n]) : (u16)0;
  }
  u16* w2f = (u16*)(g_wbuf + W2F_OFF);
  for (int e = tid0; e < 17920; e += stride) {
    int j = e & 7, l = (e >> 3) & 63, nt = (e >> 9) % 7, kt = e / 3584;
    int k = kt * 32 + ((l >> 4) << 3) + j;
    int n = nt * 16 + (l & 15);
    w2f[e] = (k < 150 && n < 100) ? f2bf(W2[k * 100 + n]) : (u16)0;
  }
  float* b1p = (float*)(g_wbuf + B1_OFF);
  for (int e = tid0; e < 160; e += stride) b1p[e] = (e < 150) ? b1[e] : 0.f;
  float* b2p = (float*)(g_wbuf + B2_OFF);
  for (int e = tid0; e < 112; e += stride) b2p[e] = (e < 100) ? b2[e] : 0.f;
}

// BM=64, 256 threads (4 waves). Wave-pair pr = wv>>1 owns rows 32pr..32pr+31
// (m-tiles 2pr, 2pr+1); wave half h = wv&1 computes the n-tile half.
// x-fragment LDS slots are XOR-swizzled by frag id (slot = fl ^ (F&7)) so a
// wave's staging stores (many k of one row) spread across 8 bank groups;
// reads use the same XOR (involution -> each lane gets its own element).
// LDS 26624 B; launch_bounds(256,4) -> ~16 waves/CU, no spill (R5-verified).
__global__ __launch_bounds__(256, 4)
void fused_mlp(const float* __restrict__ x, float* __restrict__ out, int B)
{
  __shared__ __align__(16) u16 xs[12800];   // 24576B swizzled frags + 512B compact + pad
  __shared__ float ps[2][2][64];            // [phase][half][block row] partial sums

  const int tid = threadIdx.x;
  const int lane = tid & 63;
  const int wv = tid >> 6;                  // 0..3
  const int h = wv & 1;                     // n-half
  const int pr = wv >> 1;                   // row pair
  const int cl = lane & 15, gr = lane >> 4;
  const long r0 = (long)blockIdx.x * 64;

  const u16* w1g = (const u16*)g_wbuf;
  const u16* w2g = (const u16*)(g_wbuf + W2F_OFF);

  // ---- stage x tile: coalesced float4 -> packed bf16 -> swizzled LDS ----
  const float* xg = x + r0 * 200;
  #pragma unroll
  for (int i = 0; i < 13; ++i) {
    int c = tid + i * 256;                  // 64 rows * 50 float4-chunks = 3200
    if (c < 3200) {
      int row = c / 50, kc = c % 50;
      float4 v = *reinterpret_cast<const float4*>(xg + row * 200 + kc * 4);
      int k0 = kc * 4;
      int mt = row >> 4;
      int idx;
      if (k0 < 192) {
        int F = mt * 6 + (k0 >> 5);
        int fl = (row & 15) | (((k0 & 31) >> 3) << 4);
        int slot = fl ^ (F & 7);
        idx = (F * 64 + slot) * 8 + (k0 & 7);
      } else {                              // k 192..199 -> compact region
        idx = 12288 + mt * 128 + (row & 15) * 8 + (k0 - 192);
      }
      uint2 p;
      p.x = pk2bf(v.x, v.y);
      p.y = pk2bf(v.z, v.w);
      *reinterpret_cast<uint2*>(&xs[idx]) = p;
    }
  }

  // preload kt=0 B-frags (no xs dependency -> before the barrier)
  bf16x8 bfr[5];
  #pragma unroll
  for (int nt = 0; nt < 5; ++nt)
    bfr[nt] = *reinterpret_cast<const bf16x8*>(w1g + ((0 * 10 + 5 * h + nt) * 64 + lane) * 8);

  __syncthreads();   // (1) xs fully staged

  const int mt0 = pr * 2, mt1 = pr * 2 + 1;
  const f32x4 zz = {0.f, 0.f, 0.f, 0.f};
  f32x4 acc1[2][5];
  #pragma unroll
  for (int i = 0; i < 2; ++i)
    #pragma unroll
    for (int nt = 0; nt < 5; ++nt) acc1[i][nt] = zz;

  // ---- GEMM1: [32 x 224] @ [224 x 80] per wave, 1-kt-lookahead pipeline ----
  #pragma unroll
  for (int kt = 0; kt < 7; ++kt) {
    bf16x8 bnx[5];
    if (kt < 6) {
      #pragma unroll
      for (int nt = 0; nt < 5; ++nt)
        bnx[nt] = *reinterpret_cast<const bf16x8*>(w1g + (((kt + 1) * 10 + 5 * h + nt) * 64 + lane) * 8);
    }
    bf16x8 a0, a1;
    if (kt < 6) {
      int F0 = mt0 * 6 + kt, F1 = mt1 * 6 + kt;
      a0 = *reinterpret_cast<const bf16x8*>(&xs[(F0 * 64 + (lane ^ (F0 & 7))) * 8]);
      a1 = *reinterpret_cast<const bf16x8*>(&xs[(F1 * 64 + (lane ^ (F1 & 7))) * 8]);
    } else {                                // kt==6: k 192..223, only gr==0 real
      union { bf16x8 v; u32 w[4]; } A0, A1;
      A0.v = *reinterpret_cast<const bf16x8*>(&xs[12288 + mt0 * 128 + cl * 8]);
      A1.v = *reinterpret_cast<const bf16x8*>(&xs[12288 + mt1 * 128 + cl * 8]);
      if (gr != 0) {
        A0.w[0] = A0.w[1] = A0.w[2] = A0.w[3] = 0u;
        A1.w[0] = A1.w[1] = A1.w[2] = A1.w[3] = 0u;
      }
      a0 = A0.v; a1 = A1.v;
    }
    #pragma unroll
    for (int nt = 0; nt < 5; ++nt) {
      acc1[0][nt] = __builtin_amdgcn_mfma_f32_16x16x32_bf16(a0, bfr[nt], acc1[0][nt], 0, 0, 0);
      acc1[1][nt] = __builtin_amdgcn_mfma_f32_16x16x32_bf16(a1, bfr[nt], acc1[1][nt], 0, 0, 0);
    }
    if (kt < 6) {
      #pragma unroll
      for (int nt = 0; nt < 5; ++nt) bfr[nt] = bnx[nt];
    }
  }
  __syncthreads();   // (2) all GEMM1 A-reads done before h1 overwrites xs

  // ---- epilogue 1: bias + leaky, out1 partials, h1 -> xs as GEMM2 A-frags ----
  const float* b1p = (const float*)(g_wbuf + B1_OFF);
  float b1v[5];
  #pragma unroll
  for (int nt = 0; nt < 5; ++nt) b1v[nt] = b1p[(5 * h + nt) * 16 + cl];

  float rs0[4] = {0, 0, 0, 0}, rs1[4] = {0, 0, 0, 0};
  #pragma unroll
  for (int nt = 0; nt < 5; ++nt) {
    int k2 = (5 * h + nt) * 16 + cl;        // h1 column = GEMM2 k index
    int kt2 = k2 >> 5;
    int l2base = 16 * ((k2 & 31) >> 3);
    int e2 = k2 & 7;
    #pragma unroll
    for (int j = 0; j < 4; ++j) {
      int l2 = gr * 4 + j + l2base;         // C/D: row=(lane>>4)*4+reg, col=lane&15
      float hv = acc1[0][nt][j] + b1v[nt];
      hv = (hv >= 0.f) ? hv : 0.1f * hv;
      rs0[j] += hv;
      xs[((mt0 * 5 + kt2) * 64 + l2) * 8 + e2] = f2bf(hv);
      float gv = acc1[1][nt][j] + b1v[nt];
      gv = (gv >= 0.f) ? gv : 0.1f * gv;
      rs1[j] += gv;
      xs[((mt1 * 5 + kt2) * 64 + l2) * 8 + e2] = f2bf(gv);
    }
  }
  #pragma unroll
  for (int j = 0; j < 4; ++j) {
    float s0 = rs0[j], s1 = rs1[j];
    #pragma unroll
    for (int mask = 1; mask < 16; mask <<= 1) {
      s0 += __shfl_xor(s0, mask, 64);
      s1 += __shfl_xor(s1, mask, 64);
    }
    if (cl == 0) {
      ps[0][h][mt0 * 16 + gr * 4 + j] = s0;
      ps[0][h][mt1 * 16 + gr * 4 + j] = s1;
    }
  }
  __syncthreads();   // (3) h1 frags + out1 partials visible

  if (wv == 0)       // finalize out1 (64 rows, one lane each)
    out[r0 + lane] = (ps[0][0][lane] + ps[0][1][lane]) * (1.f / 150.f);

  // ---- GEMM2: [32 x 160] @ [160 x 64/48] per wave, pipelined ----
  f32x4 acc2[2][4];
  #pragma unroll
  for (int i = 0; i < 2; ++i)
    #pragma unroll
    for (int nt = 0; nt < 4; ++nt) acc2[i][nt] = zz;

  bf16x8 b2r[4];
  #pragma unroll
  for (int nt = 0; nt < 4; ++nt)
    if (nt < 3 || h == 0)
      b2r[nt] = *reinterpret_cast<const bf16x8*>(w2g + ((0 * 7 + 4 * h + nt) * 64 + lane) * 8);

  #pragma unroll
  for (int kt = 0; kt < 5; ++kt) {
    bf16x8 bnx[4];
    if (kt < 4) {
      #pragma unroll
      for (int nt = 0; nt < 4; ++nt)
        if (nt < 3 || h == 0)
          bnx[nt] = *reinterpret_cast<const bf16x8*>(w2g + (((kt + 1) * 7 + 4 * h + nt) * 64 + lane) * 8);
    }
    bf16x8 a0 = *reinterpret_cast<const bf16x8*>(&xs[((mt0 * 5 + kt) * 64 + lane) * 8]);
    bf16x8 a1 = *reinterpret_cast<const bf16x8*>(&xs[((mt1 * 5 + kt) * 64 + lane) * 8]);
    #pragma unroll
    for (int nt = 0; nt < 4; ++nt) {
      if (nt < 3 || h == 0) {
        acc2[0][nt] = __builtin_amdgcn_mfma_f32_16x16x32_bf16(a0, b2r[nt], acc2[0][nt], 0, 0, 0);
        acc2[1][nt] = __builtin_amdgcn_mfma_f32_16x16x32_bf16(a1, b2r[nt], acc2[1][nt], 0, 0, 0);
      }
    }
    if (kt < 4) {
      #pragma unroll
      for (int nt = 0; nt < 4; ++nt)
        if (nt < 3 || h == 0) b2r[nt] = bnx[nt];
    }
  }

  // ---- epilogue 2: bias + leaky, out2 partials ----
  const float* b2p = (const float*)(g_wbuf + B2_OFF);
  float b2v[4];
  #pragma unroll
  for (int nt = 0; nt < 4; ++nt)
    b2v[nt] = (nt < 3 || h == 0) ? b2p[(4 * h + nt) * 16 + cl] : 0.f;

  float t0[4] = {0, 0, 0, 0}, t1[4] = {0, 0, 0, 0};
  #pragma unroll
  for (int nt = 0; nt < 4; ++nt) {
    if (nt < 3 || h == 0) {
      #pragma unroll
      for (int j = 0; j < 4; ++j) {
        float hv = acc2[0][nt][j] + b2v[nt];
        hv = (hv >= 0.f) ? hv : 0.1f * hv;
        t0[j] += hv;
        float gv = acc2[1][nt][j] + b2v[nt];
        gv = (gv >= 0.f) ? gv : 0.1f * gv;
        t1[j] += gv;
      }
    }
  }
  #pragma unroll
  for (int j = 0; j < 4; ++j) {
    float s0 = t0[j], s1 = t1[j];
    #pragma unroll
    for (int mask = 1; mask < 16; mask <<= 1) {
      s0 += __shfl_xor(s0, mask, 64);
      s1 += __shfl_xor(s1, mask, 64);
    }
    if (cl == 0) {
      ps[1][h][mt0 * 16 + gr * 4 + j] = s0;
      ps[1][h][mt1 * 16 + gr * 4 + j] = s1;
    }
  }
  __syncthreads();   // (4) out2 partials visible

  if (wv == 0)
    out[B + r0 + lane] = (ps[1][0][lane] + ps[1][1][lane]) * (1.f / 100.f);
}

extern "C" void kernel_launch(void* const* d_in, const int* in_sizes, int n_in,
                              void* d_out, int out_size, void* d_ws, size_t ws_size,
                              hipStream_t stream)
{
  const float* x  = (const float*)d_in[0];
  const float* W1 = (const float*)d_in[1];
  const float* b1 = (const float*)d_in[2];
  const float* W2 = (const float*)d_in[3];
  const float* b2 = (const float*)d_in[4];
  float* out = (float*)d_out;
  const int B = in_sizes[0] / 200;   // 262144

  prep_kernel<<<64, 256, 0, stream>>>(W1, b1, W2, b2);
  fused_mlp<<<B / 64, 256, 0, stream>>>(x, out, B);
}